// Round 1
// baseline (649.754 us; speedup 1.0000x reference)
//
#include <hip/hip_runtime.h>
#include <stdint.h>

typedef unsigned long long ull;

static constexpr int Bn = 4;
static constexpr int Mn = 8192;
static constexpr int Nn = 8192;
static constexpr int Dn = 64;
static constexpr int TILE = 128;
static constexpr int PADW = 68;   // LDS row stride in floats (64+4): 16B-aligned, bank-skewed

// ---- sortable-float packing: larger packed <=> (larger dot, then smaller index) ----
__device__ __forceinline__ unsigned f32_sortable(float f) {
    unsigned u = __float_as_uint(f);
    return (u & 0x80000000u) ? ~u : (u | 0x80000000u);
}
__device__ __forceinline__ float sortable_to_f32(unsigned s) {
    unsigned u = (s & 0x80000000u) ? (s ^ 0x80000000u) : ~s;
    return __uint_as_float(u);
}
__device__ __forceinline__ ull packvi(float v, int idx) {
    return ((ull)f32_sortable(v) << 32) | (ull)(0xFFFFFFFFu - (unsigned)idx);
}

// ---- init: zero the argmax tables, set m1=-1 / ms1=0 (d_out is poisoned, not re-poisoned) ----
__global__ void cm_init_kernel(ull* __restrict__ rowBestG, ull* __restrict__ colBestG,
                               float* __restrict__ out) {
    int i = blockIdx.x * blockDim.x + threadIdx.x;
    if (i < Bn * Mn) rowBestG[i] = 0ull;
    if (i < Bn * Nn) colBestG[i] = 0ull;
    if (i < Bn * Nn) {
        out[2 * Bn * Mn + i] = -1.0f;                 // m1
        out[2 * Bn * Mn + Bn * Nn + i] = 0.0f;        // ms1
    }
}

// ---- main: tiled f32 dot + fused row/col argmax ----
__global__ __launch_bounds__(256, 2) void cm_dot_argmax_kernel(
    const float* __restrict__ D0, const float* __restrict__ D1,
    ull* __restrict__ rowBestG, ull* __restrict__ colBestG)
{
    __shared__ float As[TILE * PADW];
    __shared__ float Bs[TILE * PADW];
    __shared__ ull rowRed[TILE];
    __shared__ ull colRed[TILE];

    const int b  = blockIdx.z;
    const int tm = blockIdx.y;   // row tile (image0)
    const int tn = blockIdx.x;   // col tile (image1)
    const int tid = threadIdx.x;
    const int tx = tid & 15;     // col group 0..15
    const int ty = tid >> 4;     // row group 0..15

    // Stage tiles: 128 rows x 64 floats each, as 2048 float4 per tile, 8 per thread.
    const float4* g0 = (const float4*)(D0 + (size_t)b * Mn * Dn + (size_t)tm * TILE * Dn);
    const float4* g1 = (const float4*)(D1 + (size_t)b * Nn * Dn + (size_t)tn * TILE * Dn);
    #pragma unroll
    for (int i = 0; i < 8; ++i) {
        int idx = tid + i * 256;       // float4 index within tile
        int r = idx >> 4;              // row 0..127
        int c = idx & 15;              // float4-col 0..15
        float4 va = g0[idx];
        float4 vb = g1[idx];
        *(float4*)&As[r * PADW + c * 4] = va;
        *(float4*)&Bs[r * PADW + c * 4] = vb;
    }
    if (tid < TILE) { rowRed[tid] = 0ull; colRed[tid] = 0ull; }
    __syncthreads();

    // 8x8 micro-tile per thread, STRIDED mapping: row = ty + 16*j, col = tx + 16*i
    float acc[8][8];
    #pragma unroll
    for (int j = 0; j < 8; ++j)
        #pragma unroll
        for (int i = 0; i < 8; ++i) acc[j][i] = 0.0f;

    #pragma unroll 2
    for (int k4 = 0; k4 < Dn / 4; ++k4) {
        float4 a4[8], b4[8];
        #pragma unroll
        for (int j = 0; j < 8; ++j)
            a4[j] = *(const float4*)&As[(ty + 16 * j) * PADW + k4 * 4];
        #pragma unroll
        for (int i = 0; i < 8; ++i)
            b4[i] = *(const float4*)&Bs[(tx + 16 * i) * PADW + k4 * 4];
        #pragma unroll
        for (int j = 0; j < 8; ++j)
            #pragma unroll
            for (int i = 0; i < 8; ++i) {
                acc[j][i] = fmaf(a4[j].x, b4[i].x, acc[j][i]);
                acc[j][i] = fmaf(a4[j].y, b4[i].y, acc[j][i]);
                acc[j][i] = fmaf(a4[j].z, b4[i].z, acc[j][i]);
                acc[j][i] = fmaf(a4[j].w, b4[i].w, acc[j][i]);
            }
    }

    // ---- reduce: per-row max over cols (ascending col scan => first-index tie-break) ----
    #pragma unroll
    for (int j = 0; j < 8; ++j) {
        float bv = acc[j][0];
        int bi = 0;
        #pragma unroll
        for (int i = 1; i < 8; ++i)
            if (acc[j][i] > bv) { bv = acc[j][i]; bi = i; }
        int col = tn * TILE + tx + 16 * bi;
        atomicMax(&rowRed[ty + 16 * j], packvi(bv, col));
    }
    // ---- per-col max over rows ----
    #pragma unroll
    for (int i = 0; i < 8; ++i) {
        float bv = acc[0][i];
        int bj = 0;
        #pragma unroll
        for (int j = 1; j < 8; ++j)
            if (acc[j][i] > bv) { bv = acc[j][i]; bj = j; }
        int row = tm * TILE + ty + 16 * bj;
        atomicMax(&colRed[tx + 16 * i], packvi(bv, row));
    }
    __syncthreads();

    if (tid < TILE) {
        atomicMax(&rowBestG[(size_t)b * Mn + (size_t)tm * TILE + tid], rowRed[tid]);
        atomicMax(&colBestG[(size_t)b * Nn + (size_t)tn * TILE + tid], colRed[tid]);
    }
}

// ---- finalize: mutual check, scores, scatter image1-side ----
__global__ void cm_finalize_kernel(const ull* __restrict__ rowBestG,
                                   const ull* __restrict__ colBestG,
                                   float* __restrict__ out) {
    int i = blockIdx.x * blockDim.x + threadIdx.x;   // i = b*Mn + m
    if (i >= Bn * Mn) return;
    int b = i / Mn;
    int m = i - b * Mn;
    ull p = rowBestG[i];
    float dot = sortable_to_f32((unsigned)(p >> 32));
    int n = (int)(0xFFFFFFFFu - (unsigned)p);
    ull q = colBestG[(size_t)b * Nn + n];
    int mm = (int)(0xFFFFFFFFu - (unsigned)q);
    bool mask = (mm == m);
    float dist = 1.414213f * sqrtf(fmaxf(1.0f - dot, 1e-6f));
    float score = 1.0f / (1.0f + dist);
    out[i] = mask ? (float)n : -1.0f;                       // m0
    out[Bn * Mn + i] = mask ? score : 0.0f;                 // ms0
    if (mask) {
        out[2 * Bn * Mn + (size_t)b * Nn + n] = (float)m;               // m1
        out[2 * Bn * Mn + Bn * Nn + (size_t)b * Nn + n] = score;        // ms1
    }
}

extern "C" void kernel_launch(void* const* d_in, const int* in_sizes, int n_in,
                              void* d_out, int out_size, void* d_ws, size_t ws_size,
                              hipStream_t stream) {
    const float* desc0 = (const float*)d_in[1];
    const float* desc1 = (const float*)d_in[3];
    float* out = (float*)d_out;
    ull* rowBestG = (ull*)d_ws;
    ull* colBestG = rowBestG + (size_t)Bn * Mn;

    int initN = Bn * (Mn + Nn);
    cm_init_kernel<<<dim3((initN + 255) / 256), 256, 0, stream>>>(rowBestG, colBestG, out);

    dim3 grid(Nn / TILE, Mn / TILE, Bn);
    cm_dot_argmax_kernel<<<grid, dim3(256), 0, stream>>>(desc0, desc1, rowBestG, colBestG);

    cm_finalize_kernel<<<dim3((Bn * Mn + 255) / 256), 256, 0, stream>>>(rowBestG, colBestG, out);
}